// Round 1
// baseline (511.646 us; speedup 1.0000x reference)
//
#include <hip/hip_runtime.h>
#include <hip/hip_bf16.h>

// Problem: E=1024, H=16, P=64, B=2, S=2048. All inputs/outputs f32.
// Reassociated pipeline:
//   Wp_m   = W_m @ proj_w                   [1024,64]  m in {Q,K,V}
//   Weff   = sum_h (h+1)*RW[h*64+p, e]      [64,1024]
//   lam    = exp(q1v.k1v) - exp(q2v.k2v) + lam0
//   q,k,v  = x @ Wp_m + proj_b              [B*S,64]
//   M[b]   = k[b]^T @ v[b]                  [64,64]
//   Meff   = 0.125 * (c<32 ? 1 : -lam) * M
//   G[b]   = Meff[b] @ Weff                 [64,1024]
//   out[b] = q[b] @ G[b]                    [2048,1024]

#define TS 64
#define KT 16

__global__ __launch_bounds__(256) void gemm64(
    const float* __restrict__ A, int lda, long long sA,
    const float* __restrict__ B, int ldb, long long sB,
    float* __restrict__ C, int ldc, long long sC,
    int M, int N, int K, const float* __restrict__ bias)
{
    int z = blockIdx.z;
    A += (long long)z * sA;
    B += (long long)z * sB;
    C += (long long)z * sC;
    int row0 = blockIdx.x * TS;
    int col0 = blockIdx.y * TS;

    __shared__ float As[KT][TS + 1]; // As[kk][m]
    __shared__ float Bs[KT][TS + 1]; // Bs[kk][n]

    int tid = threadIdx.x;           // 0..255
    int tx = tid & 15, ty = tid >> 4;

    float acc[4][4] = {};

    for (int k0 = 0; k0 < K; k0 += KT) {
        // A tile: 64 rows x 16 k, one float4 per thread (coalesced in k)
        {
            int m = tid >> 2, kk4 = (tid & 3) << 2;
            const float* ap = A + (long long)(row0 + m) * lda + k0 + kk4;
            float4 a4 = *reinterpret_cast<const float4*>(ap);
            As[kk4 + 0][m] = a4.x;
            As[kk4 + 1][m] = a4.y;
            As[kk4 + 2][m] = a4.z;
            As[kk4 + 3][m] = a4.w;
        }
        // B tile: 16 k x 64 n, one float4 per thread (coalesced in n)
        {
            int kb = tid >> 4, n4 = (tid & 15) << 2;
            const float* bp = B + (long long)(k0 + kb) * ldb + col0 + n4;
            float4 b4 = *reinterpret_cast<const float4*>(bp);
            Bs[kb][n4 + 0] = b4.x;
            Bs[kb][n4 + 1] = b4.y;
            Bs[kb][n4 + 2] = b4.z;
            Bs[kb][n4 + 3] = b4.w;
        }
        __syncthreads();

        #pragma unroll
        for (int kk = 0; kk < KT; ++kk) {
            float a[4], b[4];
            #pragma unroll
            for (int i = 0; i < 4; ++i) a[i] = As[kk][ty * 4 + i];
            #pragma unroll
            for (int j = 0; j < 4; ++j) b[j] = Bs[kk][tx * 4 + j];
            #pragma unroll
            for (int i = 0; i < 4; ++i)
                #pragma unroll
                for (int j = 0; j < 4; ++j)
                    acc[i][j] += a[i] * b[j];
        }
        __syncthreads();
    }

    // epilogue: float4 stores, optional bias
    float4 bv = make_float4(0.f, 0.f, 0.f, 0.f);
    if (bias) {
        const float* bp = bias + col0 + tx * 4;
        bv = *reinterpret_cast<const float4*>(bp);
    }
    #pragma unroll
    for (int i = 0; i < 4; ++i) {
        int row = row0 + ty * 4 + i;
        float4 o;
        o.x = acc[i][0] + bv.x;
        o.y = acc[i][1] + bv.y;
        o.z = acc[i][2] + bv.z;
        o.w = acc[i][3] + bv.w;
        *reinterpret_cast<float4*>(&C[(long long)row * ldc + col0 + tx * 4]) = o;
    }
}

// Weff[p][e] = sum_h (h+1) * RW[h*64+p][e]
__global__ __launch_bounds__(256) void weff_kernel(const float* __restrict__ RW,
                                                   float* __restrict__ Weff)
{
    int idx = blockIdx.x * 256 + threadIdx.x; // p*1024 + e, total 65536
    int p = idx >> 10, e = idx & 1023;
    float s = 0.f;
    #pragma unroll
    for (int h = 0; h < 16; ++h)
        s += (float)(h + 1) * RW[(h * 64 + p) * 1024 + e];
    Weff[idx] = s;
}

__global__ __launch_bounds__(256) void lam_kernel(
    const float* __restrict__ q1v, const float* __restrict__ k1v,
    const float* __restrict__ q2v, const float* __restrict__ k2v,
    const float* __restrict__ lam0, float* __restrict__ lamOut)
{
    __shared__ float red[2][4];
    int tid = threadIdx.x;
    float d1 = 0.f, d2 = 0.f;
    for (int i = tid; i < 1024; i += 256) {
        d1 += q1v[i] * k1v[i];
        d2 += q2v[i] * k2v[i];
    }
    #pragma unroll
    for (int off = 32; off > 0; off >>= 1) {
        d1 += __shfl_down(d1, off);
        d2 += __shfl_down(d2, off);
    }
    int wave = tid >> 6;
    if ((tid & 63) == 0) { red[0][wave] = d1; red[1][wave] = d2; }
    __syncthreads();
    if (tid == 0) {
        float s1 = red[0][0] + red[0][1] + red[0][2] + red[0][3];
        float s2 = red[1][0] + red[1][1] + red[1][2] + red[1][3];
        *lamOut = expf(s1) - expf(s2) + lam0[0];
    }
}

// Mpart[b][ks][c][p] = sum_{s in 32-chunk ks} k[b][s][c] * v[b][s][p]
__global__ __launch_bounds__(256) void mpart_kernel(
    const float* __restrict__ k, const float* __restrict__ v,
    float* __restrict__ Mpart)
{
    int b = blockIdx.y, ks = blockIdx.x;
    int s0 = ks * 32;
    __shared__ float ksh[32][64];
    __shared__ float vsh[32][64];
    int tid = threadIdx.x;
    const float* kb = k + ((long long)b * 2048 + s0) * 64;
    const float* vb = v + ((long long)b * 2048 + s0) * 64;
    #pragma unroll
    for (int i = 0; i < 8; ++i) {
        int lin = tid + 256 * i; // 0..2047
        int r = lin >> 6, c = lin & 63;
        ksh[r][c] = kb[lin];
        vsh[r][c] = vb[lin];
    }
    __syncthreads();
    int p = tid & 63, cg = tid >> 6; // cg in 0..3, each thread does c = cg*16..cg*16+15
    float acc[16] = {};
    for (int s = 0; s < 32; ++s) {
        float vv = vsh[s][p];
        #pragma unroll
        for (int ci = 0; ci < 16; ++ci)
            acc[ci] += ksh[s][cg * 16 + ci] * vv;
    }
    float* o = Mpart + (((long long)b * 64 + ks) * 64) * 64;
    #pragma unroll
    for (int ci = 0; ci < 16; ++ci)
        o[(cg * 16 + ci) * 64 + p] = acc[ci];
}

// Meff[b][c][p] = 0.125 * (c<32 ? 1 : -lam) * sum_ks Mpart[b][ks][c][p]
__global__ __launch_bounds__(256) void mreduce_kernel(
    const float* __restrict__ Mpart, const float* __restrict__ lamPtr,
    float* __restrict__ Meff)
{
    int idx = blockIdx.x * 256 + threadIdx.x; // total 8192
    int b = idx >> 12, cp = idx & 4095, c = cp >> 6;
    const float* base = Mpart + (long long)b * 64 * 4096 + cp;
    float s = 0.f;
    #pragma unroll 8
    for (int ks = 0; ks < 64; ++ks) s += base[ks * 4096];
    float lam = *lamPtr;
    float coef = 0.125f * (c < 32 ? 1.0f : -lam);
    Meff[idx] = s * coef;
}

extern "C" void kernel_launch(void* const* d_in, const int* in_sizes, int n_in,
                              void* d_out, int out_size, void* d_ws, size_t ws_size,
                              hipStream_t stream)
{
    const float* x      = (const float*)d_in[0];
    const float* WQ     = (const float*)d_in[1];
    const float* WK     = (const float*)d_in[2];
    const float* WV     = (const float*)d_in[3];
    const float* RW     = (const float*)d_in[4];
    const float* proj_w = (const float*)d_in[5];
    const float* proj_b = (const float*)d_in[6];
    const float* q1v    = (const float*)d_in[7];
    const float* k1v    = (const float*)d_in[8];
    const float* q2v    = (const float*)d_in[9];
    const float* k2v    = (const float*)d_in[10];
    const float* lam0   = (const float*)d_in[11];
    float* out = (float*)d_out;

    float* ws    = (float*)d_ws;
    float* Wp    = ws;               // 3*1024*64 = 196608
    float* Weff  = Wp + 196608;      // 65536
    float* lam   = Weff + 65536;     // 64
    float* qkv   = lam + 64;         // 3*4096*64 = 786432
    float* Mpart = qkv + 786432;     // 2*64*64*64 = 524288
    float* Meff  = Mpart + 524288;   // 2*64*64 = 8192
    float* G     = Meff + 8192;      // 2*64*1024 = 131072

    dim3 blk(256);

    // 1) Wp_m = W_m @ proj_w   (M=1024, N=64, K=1024)
    gemm64<<<dim3(16, 1, 1), blk, 0, stream>>>(WQ, 1024, 0, proj_w, 64, 0,
                                               Wp + 0 * 65536, 64, 0,
                                               1024, 64, 1024, nullptr);
    gemm64<<<dim3(16, 1, 1), blk, 0, stream>>>(WK, 1024, 0, proj_w, 64, 0,
                                               Wp + 1 * 65536, 64, 0,
                                               1024, 64, 1024, nullptr);
    gemm64<<<dim3(16, 1, 1), blk, 0, stream>>>(WV, 1024, 0, proj_w, 64, 0,
                                               Wp + 2 * 65536, 64, 0,
                                               1024, 64, 1024, nullptr);

    // 2) Weff
    weff_kernel<<<dim3(256), blk, 0, stream>>>(RW, Weff);

    // 3) lam
    lam_kernel<<<dim3(1), blk, 0, stream>>>(q1v, k1v, q2v, k2v, lam0, lam);

    // 4) q,k,v = x @ Wp_m + proj_b   (M=4096, N=64, K=1024)
    for (int m = 0; m < 3; ++m)
        gemm64<<<dim3(64, 1, 1), blk, 0, stream>>>(x, 1024, 0, Wp + m * 65536, 64, 0,
                                                   qkv + (long long)m * 262144, 64, 0,
                                                   4096, 64, 1024, proj_b);

    // 5) M[b] = k^T v (split-K partials, then reduce with lam/scale fold)
    mpart_kernel<<<dim3(64, 2), blk, 0, stream>>>(qkv + 262144, qkv + 2 * 262144, Mpart);
    mreduce_kernel<<<dim3(32), blk, 0, stream>>>(Mpart, lam, Meff);

    // 6) G[b] = Meff[b] @ Weff   (M=64, N=1024, K=64, batched z=2)
    gemm64<<<dim3(1, 16, 2), blk, 0, stream>>>(Meff, 64, 4096, Weff, 1024, 0,
                                               G, 1024, 65536,
                                               64, 1024, 64, nullptr);

    // 7) out[b] = q[b] @ G[b]   (M=2048, N=1024, K=64, batched z=2)
    gemm64<<<dim3(32, 16, 2), blk, 0, stream>>>(qkv, 64, 131072, G, 1024, 65536,
                                                out, 1024, 2097152,
                                                2048, 1024, 64, nullptr);
}

// Round 2
// 94.947 us; speedup vs baseline: 5.3888x; 5.3888x over previous
//
#include <hip/hip_runtime.h>
#include <hip/hip_bf16.h>

// E=1024, H=16, P=64, B=2, S=2048. All f32.
// Reassociated pipeline (verified round 1, absmax 0.5):
//   Wp[k][192] = [WQ|WK|WV](k,:) @ proj_w          (split-K x8, 3 mats fused)
//   Weff[p][e] = sum_h (h+1)*RW[h*64+p][e]
//   lam        = exp(q1v.k1v) - exp(q2v.k2v) + lam0
//   qkv[s][192]= x @ Wp + bias                     (split-K x4, 3 mats fused)
//   M[b]       = k[b]^T v[b];  Meff = 0.125*(c<32?1:-lam)*M
//   G[b]       = Meff[b] @ Weff
//   out[b]     = q[b] @ G[b]
// Split-K partials live in d_out (fully overwritten by the final GEMM).

#define TPB 256

// ---------------- fused split-K GEMM: C_part = A[rows, kslice] x B[kslice, 64] ----
// grid: (M/64, KS, 3).  z selects (A,B,C) pointer triple. nchunks = kslice/64.
__global__ __launch_bounds__(TPB) void gemm_sk(
    const float* __restrict__ a0, const float* __restrict__ a1, const float* __restrict__ a2, int lda,
    const float* __restrict__ b0, const float* __restrict__ b1, const float* __restrict__ b2, int ldb,
    float* c0, float* c1, float* c2, int ldc, long long sKS,
    int nchunks)
{
    int z = blockIdx.z;
    const float* A = (z == 0) ? a0 : (z == 1) ? a1 : a2;
    const float* B = (z == 0) ? b0 : (z == 1) ? b1 : b2;
    float* C = ((z == 0) ? c0 : (z == 1) ? c1 : c2) + (long long)blockIdx.y * sKS;

    int row0 = blockIdx.x * 64;
    int k0 = blockIdx.y * nchunks * 64;

    __shared__ float As[64][68];   // [m][k], pad 68 -> 16B-aligned rows, 2-way banks
    __shared__ float Bs[64][68];   // [k][n]

    int tid = threadIdx.x, tx = tid & 15, ty = tid >> 4;
    int lm = tid >> 4;             // 0..15, +16*r
    int lk4 = (tid & 15) * 4;

    float acc[4][4] = {};

    for (int ch = 0; ch < nchunks; ++ch, k0 += 64) {
        #pragma unroll
        for (int r = 0; r < 4; ++r) {
            int m = lm + r * 16;
            *(float4*)&As[m][lk4] = *(const float4*)&A[(long long)(row0 + m) * lda + k0 + lk4];
            *(float4*)&Bs[m][lk4] = *(const float4*)&B[(long long)(k0 + m) * ldb + lk4];
        }
        __syncthreads();

        #pragma unroll 4
        for (int kk4 = 0; kk4 < 64; kk4 += 4) {
            float4 a4[4], b4[4];
            #pragma unroll
            for (int i = 0; i < 4; ++i) a4[i] = *(const float4*)&As[ty * 4 + i][kk4];
            #pragma unroll
            for (int r = 0; r < 4; ++r) b4[r] = *(const float4*)&Bs[kk4 + r][tx * 4];
            #pragma unroll
            for (int i = 0; i < 4; ++i) {
                acc[i][0] += a4[i].x * b4[0].x + a4[i].y * b4[1].x + a4[i].z * b4[2].x + a4[i].w * b4[3].x;
                acc[i][1] += a4[i].x * b4[0].y + a4[i].y * b4[1].y + a4[i].z * b4[2].y + a4[i].w * b4[3].y;
                acc[i][2] += a4[i].x * b4[0].z + a4[i].y * b4[1].z + a4[i].z * b4[2].z + a4[i].w * b4[3].z;
                acc[i][3] += a4[i].x * b4[0].w + a4[i].y * b4[1].w + a4[i].z * b4[2].w + a4[i].w * b4[3].w;
            }
        }
        __syncthreads();
    }

    #pragma unroll
    for (int i = 0; i < 4; ++i) {
        long long m = row0 + ty * 4 + i;
        *(float4*)&C[m * ldc + tx * 4] =
            make_float4(acc[i][0], acc[i][1], acc[i][2], acc[i][3]);
    }
}

// ---------------- single-chunk K=64 batched GEMM: C = A[.,64] x B[64, N] ---------
// grid: (M/64, N/64, batch)
__global__ __launch_bounds__(TPB) void gemm_k64(
    const float* __restrict__ A, int lda, long long sA,
    const float* __restrict__ B, int ldb, long long sB,
    float* __restrict__ C, int ldc, long long sC)
{
    int z = blockIdx.z;
    A += (long long)z * sA;
    B += (long long)z * sB;
    C += (long long)z * sC;
    int row0 = blockIdx.x * 64, col0 = blockIdx.y * 64;

    __shared__ float As[64][68];
    __shared__ float Bs[64][68];

    int tid = threadIdx.x, tx = tid & 15, ty = tid >> 4;
    int lm = tid >> 4, lk4 = (tid & 15) * 4;

    #pragma unroll
    for (int r = 0; r < 4; ++r) {
        int m = lm + r * 16;
        *(float4*)&As[m][lk4] = *(const float4*)&A[(long long)(row0 + m) * lda + lk4];
        *(float4*)&Bs[m][lk4] = *(const float4*)&B[(long long)m * ldb + col0 + lk4];
    }
    __syncthreads();

    float acc[4][4] = {};
    #pragma unroll 4
    for (int kk4 = 0; kk4 < 64; kk4 += 4) {
        float4 a4[4], b4[4];
        #pragma unroll
        for (int i = 0; i < 4; ++i) a4[i] = *(const float4*)&As[ty * 4 + i][kk4];
        #pragma unroll
        for (int r = 0; r < 4; ++r) b4[r] = *(const float4*)&Bs[kk4 + r][tx * 4];
        #pragma unroll
        for (int i = 0; i < 4; ++i) {
            acc[i][0] += a4[i].x * b4[0].x + a4[i].y * b4[1].x + a4[i].z * b4[2].x + a4[i].w * b4[3].x;
            acc[i][1] += a4[i].x * b4[0].y + a4[i].y * b4[1].y + a4[i].z * b4[2].y + a4[i].w * b4[3].y;
            acc[i][2] += a4[i].x * b4[0].z + a4[i].y * b4[1].z + a4[i].z * b4[2].z + a4[i].w * b4[3].z;
            acc[i][3] += a4[i].x * b4[0].w + a4[i].y * b4[1].w + a4[i].z * b4[2].w + a4[i].w * b4[3].w;
        }
    }

    #pragma unroll
    for (int i = 0; i < 4; ++i) {
        long long m = row0 + ty * 4 + i;
        *(float4*)&C[m * ldc + col0 + tx * 4] =
            make_float4(acc[i][0], acc[i][1], acc[i][2], acc[i][3]);
    }
}

// ---------------- split-K reduce (+ optional qkv bias) --------------------------
__global__ __launch_bounds__(TPB) void reduce_add(
    const float* __restrict__ P, float* __restrict__ O,
    const float* __restrict__ bias, int n, int ks, long long stride)
{
    int idx = blockIdx.x * TPB + threadIdx.x;
    if (idx >= n) return;
    float s = 0.f;
    for (int i = 0; i < ks; ++i) s += P[idx + (long long)i * stride];
    if (bias) s += bias[(idx % 192) & 63];
    O[idx] = s;
}

// Weff[p][e] = sum_h (h+1) * RW[h*64+p][e]
__global__ __launch_bounds__(TPB) void weff_kernel(const float* __restrict__ RW,
                                                   float* __restrict__ Weff)
{
    int idx = blockIdx.x * TPB + threadIdx.x; // p*1024 + e
    int p = idx >> 10, e = idx & 1023;
    float s = 0.f;
    #pragma unroll
    for (int h = 0; h < 16; ++h)
        s += (float)(h + 1) * RW[(h * 64 + p) * 1024 + e];
    Weff[idx] = s;
}

__global__ __launch_bounds__(TPB) void lam_kernel(
    const float* __restrict__ q1v, const float* __restrict__ k1v,
    const float* __restrict__ q2v, const float* __restrict__ k2v,
    const float* __restrict__ lam0, float* __restrict__ lamOut)
{
    __shared__ float red[2][4];
    int tid = threadIdx.x;
    float d1 = 0.f, d2 = 0.f;
    for (int i = tid; i < 1024; i += TPB) {
        d1 += q1v[i] * k1v[i];
        d2 += q2v[i] * k2v[i];
    }
    #pragma unroll
    for (int off = 32; off > 0; off >>= 1) {
        d1 += __shfl_down(d1, off);
        d2 += __shfl_down(d2, off);
    }
    int wave = tid >> 6;
    if ((tid & 63) == 0) { red[0][wave] = d1; red[1][wave] = d2; }
    __syncthreads();
    if (tid == 0) {
        float s1 = red[0][0] + red[0][1] + red[0][2] + red[0][3];
        float s2 = red[1][0] + red[1][1] + red[1][2] + red[1][3];
        *lamOut = expf(s1) - expf(s2) + lam0[0];
    }
}

// Mpart[b][ks][c][p] over 32-row chunks; k = qkv cols 64..127, v = cols 128..191
__global__ __launch_bounds__(TPB) void mpart_kernel(
    const float* __restrict__ qkv, float* __restrict__ Mpart)
{
    int b = blockIdx.y, ks = blockIdx.x;
    int s0 = ks * 32;
    __shared__ float ksh[32][64];
    __shared__ float vsh[32][64];
    int tid = threadIdx.x;
    const float* base = qkv + ((long long)(b * 2048 + s0)) * 192;
    #pragma unroll
    for (int i = 0; i < 2; ++i) {
        int lin = tid + TPB * i;       // 0..511 float4 units
        int r = lin >> 4, c4 = (lin & 15) * 4;
        *(float4*)&ksh[r][c4] = *(const float4*)&base[(long long)r * 192 + 64 + c4];
        *(float4*)&vsh[r][c4] = *(const float4*)&base[(long long)r * 192 + 128 + c4];
    }
    __syncthreads();
    int p = tid & 63, cg = tid >> 6;
    float acc[16] = {};
    for (int s = 0; s < 32; ++s) {
        float vv = vsh[s][p];
        #pragma unroll
        for (int ci = 0; ci < 16; ++ci)
            acc[ci] += ksh[s][cg * 16 + ci] * vv;
    }
    float* o = Mpart + ((long long)b * 64 + ks) * 4096;
    #pragma unroll
    for (int ci = 0; ci < 16; ++ci)
        o[(cg * 16 + ci) * 64 + p] = acc[ci];
}

// Meff[b][c][p] = 0.125 * (c<32 ? 1 : -lam) * sum_ks Mpart[b][ks][c][p]
__global__ __launch_bounds__(TPB) void mreduce_kernel(
    const float* __restrict__ Mpart, const float* __restrict__ lamPtr,
    float* __restrict__ Meff)
{
    int idx = blockIdx.x * TPB + threadIdx.x; // 8192 total
    int b = idx >> 12, cp = idx & 4095, c = cp >> 6;
    const float* base = Mpart + (long long)b * 64 * 4096 + cp;
    float s = 0.f;
    #pragma unroll 8
    for (int ks = 0; ks < 64; ++ks) s += base[(long long)ks * 4096];
    float lam = *lamPtr;
    float coef = 0.125f * (c < 32 ? 1.0f : -lam);
    Meff[idx] = s * coef;
}

extern "C" void kernel_launch(void* const* d_in, const int* in_sizes, int n_in,
                              void* d_out, int out_size, void* d_ws, size_t ws_size,
                              hipStream_t stream)
{
    const float* x      = (const float*)d_in[0];
    const float* WQ     = (const float*)d_in[1];
    const float* WK     = (const float*)d_in[2];
    const float* WV     = (const float*)d_in[3];
    const float* RW     = (const float*)d_in[4];
    const float* proj_w = (const float*)d_in[5];
    const float* proj_b = (const float*)d_in[6];
    const float* q1v    = (const float*)d_in[7];
    const float* k1v    = (const float*)d_in[8];
    const float* q2v    = (const float*)d_in[9];
    const float* k2v    = (const float*)d_in[10];
    const float* lam0   = (const float*)d_in[11];
    float* out = (float*)d_out;

    float* ws    = (float*)d_ws;
    float* Wp    = ws;               // 1024*192 = 196608
    float* Weff  = Wp + 196608;      // 65536
    float* lam   = Weff + 65536;     // 64
    float* qkv   = lam + 64;         // 4096*192 = 786432
    float* Mpart = qkv + 786432;     // 2*64*64*64 = 524288
    float* Meff  = Mpart + 524288;   // 8192
    float* G     = Meff + 8192;      // 2*64*1024 = 131072
    float* part  = out;              // split-K partials scratch (d_out, overwritten later)

    dim3 blk(TPB);

    // 1) Wp = [WQ|WK|WV] @ proj_w, split-K x8 (kslice=128, 2 chunks), 384 blocks
    gemm_sk<<<dim3(16, 8, 3), blk, 0, stream>>>(
        WQ, WK, WV, 1024,
        proj_w, proj_w, proj_w, 64,
        part, part + 64, part + 128, 192, 196608LL, 2);
    reduce_add<<<dim3(768), blk, 0, stream>>>(part, Wp, nullptr, 196608, 8, 196608LL);

    // 2) Weff, lam (independent)
    weff_kernel<<<dim3(256), blk, 0, stream>>>(RW, Weff);
    lam_kernel<<<dim3(1), blk, 0, stream>>>(q1v, k1v, q2v, k2v, lam0, lam);

    // 3) qkv = x @ Wp + bias, split-K x4 (kslice=256, 4 chunks), 768 blocks
    gemm_sk<<<dim3(64, 4, 3), blk, 0, stream>>>(
        x, x, x, 1024,
        Wp, Wp + 64, Wp + 128, 192,
        part, part + 64, part + 128, 192, 786432LL, 4);
    reduce_add<<<dim3(3072), blk, 0, stream>>>(part, qkv, proj_b, 786432, 4, 786432LL);

    // 4) M[b] = k^T v partials, then fold lam/scale
    mpart_kernel<<<dim3(64, 2), blk, 0, stream>>>(qkv, Mpart);
    mreduce_kernel<<<dim3(32), blk, 0, stream>>>(Mpart, lam, Meff);

    // 5) G[b] = Meff[b] @ Weff   (M=64, N=1024, K=64)
    gemm_k64<<<dim3(1, 16, 2), blk, 0, stream>>>(
        Meff, 64, 4096, Weff, 1024, 0, G, 1024, 65536);

    // 6) out[b] = q[b] @ G[b]    (M=2048, N=1024, K=64) — overwrites scratch
    gemm_k64<<<dim3(32, 16, 2), blk, 0, stream>>>(
        qkv, 192, 393216, G, 1024, 65536, out, 1024, 2097152);
}

// Round 3
// 78.174 us; speedup vs baseline: 6.5449x; 1.2145x over previous
//
#include <hip/hip_runtime.h>
#include <hip/hip_bf16.h>

// E=1024, H=16, P=64, B=2, S=2048. All f32 in/out.
// Reassociated pipeline (verified rounds 1-2, absmax 0.25):
//   Wp[k][192] = [WQ|WK|WV] @ proj_w        -> stored as bf16 hi/lo, TRANSPOSED [192][1024]
//   Weff[p][e] = sum_h (h+1)*RW[h*64+p][e]  (f32)
//   lam        = exp(q1v.k1v) - exp(q2v.k2v) + lam0
//   qkv        = x @ Wp (+bias deferred)    -> f32 split-K partials (q,k,v separate)
//   M[b]       = k^T v; Meff = 0.125*(c<32?1:-lam)*M
//   G[b]       = Meff @ Weff                -> stored bf16 hi/lo TRANSPOSED GT[e][c]
//   out[b]     = q @ G                      (f32)
// Big GEMMs use split-bf16 MFMA: A*B ~= Ahi*Bhi + Ahi*Blo + Alo*Bhi (rel err ~1e-4).

typedef __attribute__((ext_vector_type(8))) short short8;
typedef __attribute__((ext_vector_type(4))) float f32x4;
typedef unsigned short ushort_t;
typedef unsigned int uint_t;

__device__ inline ushort_t f2bf(float v) {
    uint_t u = __float_as_uint(v);
    return (ushort_t)((u + 0x7FFF + ((u >> 16) & 1)) >> 16);   // RNE
}
__device__ inline float bf2f(ushort_t h) { return __uint_as_float(((uint_t)h) << 16); }
__device__ inline void split2(float v, ushort_t& hi, ushort_t& lo) {
    hi = f2bf(v);
    lo = f2bf(v - bf2f(hi));
}
__device__ inline int swzA(int row, int k) { return (row * 64 + k) ^ ((row & 7) << 3); }

// 64x64-output MFMA tile over K chunks of 64. 256 threads = 4 waves, wave w owns
// rows w*16..w*16+15, 4 col-blocks of 16. A: f32 (split on the fly). B: either
// f32 (CVTB, split+transpose on the fly) or preconverted transposed bf16 planes.
template<bool CVTB>
__device__ void mfma_tile64(const float* __restrict__ A, int lda,
                            const float* __restrict__ Bf, int ldbf,
                            const ushort_t* __restrict__ Bthi, const ushort_t* __restrict__ Btlo,
                            int ldbt, int k0, int nchunks, f32x4 acc[4])
{
    __shared__ __align__(16) ushort_t Ah[4096], Al[4096], Bh[4096], Bl[4096];
    int tid = threadIdx.x;
    int wave = tid >> 6, lane = tid & 63;
    int rl = lane & 15, kg = lane >> 4;

    for (int ch = 0; ch < nchunks; ++ch, k0 += 64) {
        // ---- stage A (64 rows x 64 k, f32 -> split bf16, swizzled) ----
        #pragma unroll
        for (int i = 0; i < 4; ++i) {
            int pos = tid + 256 * i;
            int r = pos >> 4, k4 = (pos & 15) * 4;
            float4 v = *(const float4*)&A[(long long)r * lda + k0 + k4];
            ushort4 h, l;
            split2(v.x, h.x, l.x); split2(v.y, h.y, l.y);
            split2(v.z, h.z, l.z); split2(v.w, h.w, l.w);
            int idx = swzA(r, k4);
            *(ushort4*)&Ah[idx] = h;
            *(ushort4*)&Al[idx] = l;
        }
        // ---- stage B (as Bt[col][k]) ----
        if (CVTB) {
            #pragma unroll
            for (int i = 0; i < 4; ++i) {
                int pos = tid + 256 * i;
                int kk = pos >> 4, n4 = (pos & 15) * 4;
                float4 v = *(const float4*)&Bf[(long long)(k0 + kk) * ldbf + n4];
                float vv[4] = {v.x, v.y, v.z, v.w};
                #pragma unroll
                for (int j = 0; j < 4; ++j) {
                    ushort_t h, l; split2(vv[j], h, l);
                    int n = n4 + j;
                    int idx = swzA(n, kk);
                    Bh[idx] = h; Bl[idx] = l;
                }
            }
        } else {
            #pragma unroll
            for (int i = 0; i < 2; ++i) {
                int pos = tid + 256 * i;       // 512 positions: 64 cols x 8 k-groups
                int n = pos >> 3, k8 = (pos & 7) * 8;
                int idx = swzA(n, k8);
                *(short8*)&Bh[idx] = *(const short8*)&Bthi[(long long)n * ldbt + k0 + k8];
                *(short8*)&Bl[idx] = *(const short8*)&Btlo[(long long)n * ldbt + k0 + k8];
            }
        }
        __syncthreads();

        // ---- compute: 2 K-steps x 4 col-blocks x 3 split-MFMAs ----
        int ar = wave * 16 + rl;
        #pragma unroll
        for (int ks = 0; ks < 2; ++ks) {
            int kb = ks * 32 + kg * 8;
            int ai = swzA(ar, kb);
            short8 ah = *(const short8*)&Ah[ai];
            short8 al = *(const short8*)&Al[ai];
            #pragma unroll
            for (int n = 0; n < 4; ++n) {
                int bc = n * 16 + rl;
                int bi = swzA(bc, kb);
                short8 bh = *(const short8*)&Bh[bi];
                short8 bl = *(const short8*)&Bl[bi];
                acc[n] = __builtin_amdgcn_mfma_f32_16x16x32_bf16(ah, bh, acc[n], 0, 0, 0);
                acc[n] = __builtin_amdgcn_mfma_f32_16x16x32_bf16(ah, bl, acc[n], 0, 0, 0);
                acc[n] = __builtin_amdgcn_mfma_f32_16x16x32_bf16(al, bh, acc[n], 0, 0, 0);
            }
        }
        __syncthreads();
    }
}

// K1: Wp split-K partials. grid 192: slice(4) x z(3) x rowblk(16)
__global__ __launch_bounds__(256) void prep_sk(
    const float* __restrict__ WQ, const float* __restrict__ WK, const float* __restrict__ WV,
    const float* __restrict__ proj_w, float* __restrict__ wppart)
{
    int bid = blockIdx.x;
    int slice = bid / 48, t = bid % 48, z = t / 16, rowblk = t % 16;
    const float* A = ((z == 0) ? WQ : (z == 1) ? WK : WV) + (long long)rowblk * 64 * 1024;
    f32x4 acc[4] = {};
    mfma_tile64<true>(A, 1024, proj_w, 64, nullptr, nullptr, 0, slice * 256, 4, acc);
    float* C = wppart + (long long)(slice * 3 + z) * 65536 + (long long)rowblk * 64 * 64;
    int lane = threadIdx.x & 63, wave = threadIdx.x >> 6;
    #pragma unroll
    for (int n = 0; n < 4; ++n) {
        int col = n * 16 + (lane & 15);
        #pragma unroll
        for (int j = 0; j < 4; ++j) {
            int row = wave * 16 + (lane >> 4) * 4 + j;
            C[row * 64 + col] = acc[n][j];
        }
    }
}

// K2: reduce Wp partials -> WpT bf16 planes; Weff; lam. grid 257.
__global__ __launch_bounds__(256) void wpfix(
    const float* __restrict__ wppart, const float* __restrict__ RW,
    const float* __restrict__ q1v, const float* __restrict__ k1v,
    const float* __restrict__ q2v, const float* __restrict__ k2v,
    const float* __restrict__ lam0,
    ushort_t* __restrict__ WpThi, ushort_t* __restrict__ WpTlo,
    float* __restrict__ Weff, float* __restrict__ lamOut)
{
    __shared__ float red[2][4];
    int bid = blockIdx.x, tid = threadIdx.x;
    if (bid < 192) {
        int f4i = bid * 256 + tid;          // over [1024 rows][48 f4-cols]
        int row = f4i / 48, cq = f4i % 48;
        int c4 = cq * 4, z = c4 >> 6, cl = c4 & 63;
        float4 s = {0.f, 0.f, 0.f, 0.f};
        #pragma unroll
        for (int sl = 0; sl < 4; ++sl) {
            float4 m = *(const float4*)&wppart[(long long)(sl * 3 + z) * 65536 + (long long)row * 64 + cl];
            s.x += m.x; s.y += m.y; s.z += m.z; s.w += m.w;
        }
        float vv[4] = {s.x, s.y, s.z, s.w};
        #pragma unroll
        for (int j = 0; j < 4; ++j) {
            ushort_t h, l; split2(vv[j], h, l);
            WpThi[(long long)(c4 + j) * 1024 + row] = h;
            WpTlo[(long long)(c4 + j) * 1024 + row] = l;
        }
    } else if (bid < 256) {
        int f4i = (bid - 192) * 256 + tid;  // 16384 f4 over Weff[64][1024]
        int p = f4i >> 8, e4 = (f4i & 255) * 4;
        float4 s = {0.f, 0.f, 0.f, 0.f};
        #pragma unroll
        for (int h = 0; h < 16; ++h) {
            float4 r = *(const float4*)&RW[(long long)(h * 64 + p) * 1024 + e4];
            float m = (float)(h + 1);
            s.x += m * r.x; s.y += m * r.y; s.z += m * r.z; s.w += m * r.w;
        }
        *(float4*)&Weff[(long long)p * 1024 + e4] = s;
    } else {
        float d1 = 0.f, d2 = 0.f;
        for (int i = tid; i < 1024; i += 256) {
            d1 += q1v[i] * k1v[i];
            d2 += q2v[i] * k2v[i];
        }
        #pragma unroll
        for (int off = 32; off > 0; off >>= 1) {
            d1 += __shfl_down(d1, off);
            d2 += __shfl_down(d2, off);
        }
        int wave = tid >> 6;
        if ((tid & 63) == 0) { red[0][wave] = d1; red[1][wave] = d2; }
        __syncthreads();
        if (tid == 0) {
            float s1 = red[0][0] + red[0][1] + red[0][2] + red[0][3];
            float s2 = red[1][0] + red[1][1] + red[1][2] + red[1][3];
            *lamOut = expf(s1) - expf(s2) + lam0[0];
        }
    }
}

// K3: qkv split-K partials (no bias). grid 384: slice(2) x z(3) x rowblk(64)
__global__ __launch_bounds__(256) void qkv_sk(
    const float* __restrict__ x,
    const ushort_t* __restrict__ WpThi, const ushort_t* __restrict__ WpTlo,
    float* __restrict__ qpart)
{
    int bid = blockIdx.x;
    int slice = bid / 192, t = bid % 192, z = t / 64, rowblk = t % 64;
    const float* A = x + (long long)rowblk * 64 * 1024;
    f32x4 acc[4] = {};
    mfma_tile64<false>(A, 1024, nullptr, 0,
                       WpThi + (long long)z * 64 * 1024, WpTlo + (long long)z * 64 * 1024, 1024,
                       slice * 512, 8, acc);
    float* C = qpart + (long long)(slice * 3 + z) * 262144 + (long long)rowblk * 64 * 64;
    int lane = threadIdx.x & 63, wave = threadIdx.x >> 6;
    #pragma unroll
    for (int n = 0; n < 4; ++n) {
        int col = n * 16 + (lane & 15);
        #pragma unroll
        for (int j = 0; j < 4; ++j) {
            int row = wave * 16 + (lane >> 4) * 4 + j;
            C[row * 64 + col] = acc[n][j];
        }
    }
}

// K4: M partials; k,v reduced from qpart slices (+bias) inline. grid 64: ks(32) x b(2)
__global__ __launch_bounds__(256) void mpart_k(
    const float* __restrict__ qpart, const float* __restrict__ proj_b,
    float* __restrict__ Mpart)
{
    int ks = blockIdx.x & 31, b = blockIdx.x >> 5;
    __shared__ float ksh[64][68];
    __shared__ float vsh[64][68];
    int tid = threadIdx.x;
    long long row0 = (long long)b * 2048 + ks * 64;
    #pragma unroll
    for (int i = 0; i < 8; ++i) {
        int pos = tid + 256 * i;        // 2048 f4: [arr(2)][row(64)][c4(16)]
        int arr = pos >> 10, rem = pos & 1023;
        int r = rem >> 4, c4 = (rem & 15) * 4;
        const float* s0 = qpart + (long long)(1 + arr) * 262144 + (row0 + r) * 64 + c4;
        const float* s1 = qpart + (long long)(4 + arr) * 262144 + (row0 + r) * 64 + c4;
        float4 a = *(const float4*)s0, c = *(const float4*)s1;
        float4 bb = *(const float4*)&proj_b[c4];
        float4 v = {a.x + c.x + bb.x, a.y + c.y + bb.y, a.z + c.z + bb.z, a.w + c.w + bb.w};
        if (arr == 0) *(float4*)&ksh[r][c4] = v;
        else          *(float4*)&vsh[r][c4] = v;
    }
    __syncthreads();
    int p = tid & 63, cg = tid >> 6;
    float acc[16] = {};
    for (int s = 0; s < 64; ++s) {
        float vv = vsh[s][p];
        float4 k0 = *(const float4*)&ksh[s][cg * 16];
        float4 k1 = *(const float4*)&ksh[s][cg * 16 + 4];
        float4 k2 = *(const float4*)&ksh[s][cg * 16 + 8];
        float4 k3 = *(const float4*)&ksh[s][cg * 16 + 12];
        acc[0] += k0.x * vv;  acc[1] += k0.y * vv;  acc[2] += k0.z * vv;  acc[3] += k0.w * vv;
        acc[4] += k1.x * vv;  acc[5] += k1.y * vv;  acc[6] += k1.z * vv;  acc[7] += k1.w * vv;
        acc[8] += k2.x * vv;  acc[9] += k2.y * vv;  acc[10] += k2.z * vv; acc[11] += k2.w * vv;
        acc[12] += k3.x * vv; acc[13] += k3.y * vv; acc[14] += k3.z * vv; acc[15] += k3.w * vv;
    }
    float* o = Mpart + (long long)b * 131072 + (long long)ks * 4096;
    #pragma unroll
    for (int ci = 0; ci < 16; ++ci)
        o[(cg * 16 + ci) * 64 + p] = acc[ci];
}

// K5: Meff = coef * sum(Mpart); G = Meff @ Weff -> GT bf16 planes. grid 32: colblk(16) x b(2)
__global__ __launch_bounds__(256) void gkern(
    const float* __restrict__ Mpart, const float* __restrict__ Weff,
    const float* __restrict__ lamp,
    ushort_t* __restrict__ GThi, ushort_t* __restrict__ GTlo)
{
    int colblk = blockIdx.x & 15, b = blockIdx.x >> 4;
    __shared__ float As[64][68];
    __shared__ float Bs[64][68];
    int tid = threadIdx.x;
    float lam = *lamp;
    #pragma unroll
    for (int i = 0; i < 4; ++i) {
        int pos = tid + 256 * i;        // 1024 f4 over Meff[64][64]
        int c = pos >> 4, p4 = (pos & 15) * 4;
        float4 s = {0.f, 0.f, 0.f, 0.f};
        for (int ks = 0; ks < 32; ++ks) {
            float4 m = *(const float4*)&Mpart[(long long)b * 131072 + (long long)ks * 4096 + c * 64 + p4];
            s.x += m.x; s.y += m.y; s.z += m.z; s.w += m.w;
        }
        float coef = 0.125f * (c < 32 ? 1.0f : -lam);
        s.x *= coef; s.y *= coef; s.z *= coef; s.w *= coef;
        *(float4*)&As[c][p4] = s;
    }
    #pragma unroll
    for (int i = 0; i < 4; ++i) {
        int pos = tid + 256 * i;
        int kk = pos >> 4, n4 = (pos & 15) * 4;
        *(float4*)&Bs[kk][n4] = *(const float4*)&Weff[(long long)kk * 1024 + colblk * 64 + n4];
    }
    __syncthreads();

    int tx = tid & 15, ty = tid >> 4;
    float acc[4][4] = {};
    #pragma unroll 4
    for (int kk4 = 0; kk4 < 64; kk4 += 4) {
        float4 a4[4], b4[4];
        #pragma unroll
        for (int i = 0; i < 4; ++i) a4[i] = *(const float4*)&As[ty * 4 + i][kk4];
        #pragma unroll
        for (int r = 0; r < 4; ++r) b4[r] = *(const float4*)&Bs[kk4 + r][tx * 4];
        #pragma unroll
        for (int i = 0; i < 4; ++i) {
            acc[i][0] += a4[i].x * b4[0].x + a4[i].y * b4[1].x + a4[i].z * b4[2].x + a4[i].w * b4[3].x;
            acc[i][1] += a4[i].x * b4[0].y + a4[i].y * b4[1].y + a4[i].z * b4[2].y + a4[i].w * b4[3].y;
            acc[i][2] += a4[i].x * b4[0].z + a4[i].y * b4[1].z + a4[i].z * b4[2].z + a4[i].w * b4[3].z;
            acc[i][3] += a4[i].x * b4[0].w + a4[i].y * b4[1].w + a4[i].z * b4[2].w + a4[i].w * b4[3].w;
        }
    }
    #pragma unroll
    for (int i = 0; i < 4; ++i)
        #pragma unroll
        for (int j = 0; j < 4; ++j) {
            ushort_t h, l; split2(acc[i][j], h, l);
            long long idx = (long long)b * 65536 + (long long)(colblk * 64 + tx * 4 + j) * 64 + ty * 4 + i;
            GThi[idx] = h; GTlo[idx] = l;
        }
}

// K6: out = q @ G, q reduced from qpart (+bias) and split inline. grid 1024.
__global__ __launch_bounds__(256) void outk(
    const float* __restrict__ qpart, const float* __restrict__ proj_b,
    const ushort_t* __restrict__ GThi, const ushort_t* __restrict__ GTlo,
    float* __restrict__ out)
{
    int bid = blockIdx.x;
    int rowblk = bid & 31, colblk = (bid >> 5) & 15, b = bid >> 9;
    __shared__ __align__(16) ushort_t Ah[4096], Al[4096], Bh[4096], Bl[4096];
    int tid = threadIdx.x;
    long long row0 = (long long)b * 2048 + rowblk * 64;

    #pragma unroll
    for (int i = 0; i < 4; ++i) {
        int pos = tid + 256 * i;
        int r = pos >> 4, k4 = (pos & 15) * 4;
        float4 a = *(const float4*)&qpart[(row0 + r) * 64 + k4];
        float4 c = *(const float4*)&qpart[(long long)3 * 262144 + (row0 + r) * 64 + k4];
        float4 bb = *(const float4*)&proj_b[k4];
        float v[4] = {a.x + c.x + bb.x, a.y + c.y + bb.y, a.z + c.z + bb.z, a.w + c.w + bb.w};
        ushort4 h, l;
        split2(v[0], h.x, l.x); split2(v[1], h.y, l.y);
        split2(v[2], h.z, l.z); split2(v[3], h.w, l.w);
        int idx = swzA(r, k4);
        *(ushort4*)&Ah[idx] = h;
        *(ushort4*)&Al[idx] = l;
    }
    #pragma unroll
    for (int i = 0; i < 2; ++i) {
        int pos = tid + 256 * i;
        int n = pos >> 3, k8 = (pos & 7) * 8;
        int idx = swzA(n, k8);
        long long g = (long long)b * 65536 + (long long)(colblk * 64 + n) * 64 + k8;
        *(short8*)&Bh[idx] = *(const short8*)&GThi[g];
        *(short8*)&Bl[idx] = *(const short8*)&GTlo[g];
    }
    __syncthreads();

    int wave = tid >> 6, lane = tid & 63;
    int rl = lane & 15, kg = lane >> 4;
    f32x4 acc[4] = {};
    int ar = wave * 16 + rl;
    #pragma unroll
    for (int ks = 0; ks < 2; ++ks) {
        int kb = ks * 32 + kg * 8;
        int ai = swzA(ar, kb);
        short8 ah = *(const short8*)&Ah[ai];
        short8 al = *(const short8*)&Al[ai];
        #pragma unroll
        for (int n = 0; n < 4; ++n) {
            int bc = n * 16 + rl;
            int bi = swzA(bc, kb);
            short8 bh = *(const short8*)&Bh[bi];
            short8 bl = *(const short8*)&Bl[bi];
            acc[n] = __builtin_amdgcn_mfma_f32_16x16x32_bf16(ah, bh, acc[n], 0, 0, 0);
            acc[n] = __builtin_amdgcn_mfma_f32_16x16x32_bf16(ah, bl, acc[n], 0, 0, 0);
            acc[n] = __builtin_amdgcn_mfma_f32_16x16x32_bf16(al, bh, acc[n], 0, 0, 0);
        }
    }
    #pragma unroll
    for (int n = 0; n < 4; ++n) {
        int col = colblk * 64 + n * 16 + rl;
        #pragma unroll
        for (int j = 0; j < 4; ++j) {
            int row = rowblk * 64 + wave * 16 + (lane >> 4) * 4 + j;
            out[(long long)b * 2097152 + (long long)row * 1024 + col] = acc[n][j];
        }
    }
}

extern "C" void kernel_launch(void* const* d_in, const int* in_sizes, int n_in,
                              void* d_out, int out_size, void* d_ws, size_t ws_size,
                              hipStream_t stream)
{
    const float* x      = (const float*)d_in[0];
    const float* WQ     = (const float*)d_in[1];
    const float* WK     = (const float*)d_in[2];
    const float* WV     = (const float*)d_in[3];
    const float* RW     = (const float*)d_in[4];
    const float* proj_w = (const float*)d_in[5];
    const float* proj_b = (const float*)d_in[6];
    const float* q1v    = (const float*)d_in[7];
    const float* k1v    = (const float*)d_in[8];
    const float* q2v    = (const float*)d_in[9];
    const float* k2v    = (const float*)d_in[10];
    const float* lam0   = (const float*)d_in[11];
    float* out = (float*)d_out;

    float* ws      = (float*)d_ws;
    float* wppart  = ws;                       // 4*3*65536   = 786432
    float* qpart   = ws + 786432;              // 2*3*262144  = 1572864
    float* Mpart   = ws + 2359296;             // 2*32*4096   = 262144
    float* Weff    = ws + 2621440;             // 65536
    float* lam     = ws + 2686976;             // 16
    ushort_t* ub   = (ushort_t*)(ws + 2687040);
    ushort_t* WpThi = ub;                      // 192*1024 = 196608
    ushort_t* WpTlo = ub + 196608;
    ushort_t* GThi  = ub + 393216;             // 2*1024*64 = 131072
    ushort_t* GTlo  = ub + 524288;

    dim3 blk(256);
    prep_sk<<<dim3(192), blk, 0, stream>>>(WQ, WK, WV, proj_w, wppart);
    wpfix<<<dim3(257), blk, 0, stream>>>(wppart, RW, q1v, k1v, q2v, k2v, lam0,
                                         WpThi, WpTlo, Weff, lam);
    qkv_sk<<<dim3(384), blk, 0, stream>>>(x, WpThi, WpTlo, qpart);
    mpart_k<<<dim3(64), blk, 0, stream>>>(qpart, proj_b, Mpart);
    gkern<<<dim3(32), blk, 0, stream>>>(Mpart, Weff, lam, GThi, GTlo);
    outk<<<dim3(1024), blk, 0, stream>>>(qpart, proj_b, GThi, GTlo, out);
}

// Round 4
// 60.875 us; speedup vs baseline: 8.4049x; 1.2842x over previous
//
#include <hip/hip_runtime.h>
#include <hip/hip_bf16.h>

// E=1024, H=16, P=64, B=2, S=2048. All f32 in/out.
// Pipeline (algebra verified rounds 1-3, absmax <= 0.5):
//   Wp[k][192] = [WQ|WK|WV] @ proj_w      (split-K x8 MFMA partials)
//   WpT planes = reduce+split bf16, transposed [192][1024]
//   Weff[p][e] = sum_h (h+1)*RW[h*64+p][e]; lam = exp(q1.k1)-exp(q2.k2)+lam0
//   qkv        = x @ Wp (z-fused, split-K x8 partials, bias deferred)
//   Q planes   = reduce(q)+bias -> bf16 hi/lo [4096][64]
//   M[b]       = k^T v partials (reduce k,v inline); Meff = 0.125*(c<32?1:-lam)*M
//   G[b]       = Meff @ Weff -> GT bf16 planes [b][1024][64]
//   out[b]     = Q @ G via MFMA
// Split-bf16 MFMA: A*B ~= Ahi*Bhi + Ahi*Blo + Alo*Bhi (rel err ~1e-4).

typedef __attribute__((ext_vector_type(8))) short short8;
typedef __attribute__((ext_vector_type(4))) float f32x4;
typedef unsigned short ushort_t;
typedef unsigned int uint_t;

__device__ inline ushort_t f2bf(float v) {
    uint_t u = __float_as_uint(v);
    return (ushort_t)((u + 0x7FFF + ((u >> 16) & 1)) >> 16);   // RNE
}
__device__ inline float bf2f(ushort_t h) { return __uint_as_float(((uint_t)h) << 16); }
__device__ inline void split2(float v, ushort_t& hi, ushort_t& lo) {
    hi = f2bf(v);
    lo = f2bf(v - bf2f(hi));
}
__device__ inline int swzA(int row, int k) { return (row * 64 + k) ^ ((row & 7) << 3); }

// ---------------- K1: Wp split-K partials. grid 384 = slice(8) x z(3) x rowblk(16)
__global__ __launch_bounds__(256) void prep_sk(
    const float* __restrict__ WQ, const float* __restrict__ WK, const float* __restrict__ WV,
    const float* __restrict__ proj_w, float* __restrict__ wppart)
{
    __shared__ __align__(16) ushort_t Ah[4096], Al[4096], Bh[4096], Bl[4096];
    int bid = blockIdx.x;
    int slice = bid / 48, t = bid % 48, z = t / 16, rowblk = t % 16;
    const float* A = ((z == 0) ? WQ : (z == 1) ? WK : WV) + (long long)rowblk * 64 * 1024;

    int tid = threadIdx.x;
    int wave = tid >> 6, lane = tid & 63;
    int rl = lane & 15, kg = lane >> 4;
    f32x4 acc[4] = {};

    int k0 = slice * 128;
    for (int ch = 0; ch < 2; ++ch, k0 += 64) {
        #pragma unroll
        for (int i = 0; i < 4; ++i) {
            int pos = tid + 256 * i;
            int r = pos >> 4, k4 = (pos & 15) * 4;
            float4 v = *(const float4*)&A[(long long)r * 1024 + k0 + k4];
            ushort4 h, l;
            split2(v.x, h.x, l.x); split2(v.y, h.y, l.y);
            split2(v.z, h.z, l.z); split2(v.w, h.w, l.w);
            int idx = swzA(r, k4);
            *(ushort4*)&Ah[idx] = h;
            *(ushort4*)&Al[idx] = l;
        }
        // B = proj_w chunk [64k][64n], split + transpose into [n][k]
        #pragma unroll
        for (int i = 0; i < 4; ++i) {
            int pos = tid + 256 * i;
            int kk = pos >> 4, n4 = (pos & 15) * 4;
            float4 v = *(const float4*)&proj_w[(long long)(k0 + kk) * 64 + n4];
            float vv[4] = {v.x, v.y, v.z, v.w};
            #pragma unroll
            for (int j = 0; j < 4; ++j) {
                ushort_t h, l; split2(vv[j], h, l);
                int idx = swzA(n4 + j, kk);
                Bh[idx] = h; Bl[idx] = l;
            }
        }
        __syncthreads();
        int ar = wave * 16 + rl;
        #pragma unroll
        for (int ks = 0; ks < 2; ++ks) {
            int kb = ks * 32 + kg * 8;
            short8 ah = *(const short8*)&Ah[swzA(ar, kb)];
            short8 al = *(const short8*)&Al[swzA(ar, kb)];
            #pragma unroll
            for (int n = 0; n < 4; ++n) {
                int bi = swzA(n * 16 + rl, kb);
                short8 bh = *(const short8*)&Bh[bi];
                short8 bl = *(const short8*)&Bl[bi];
                acc[n] = __builtin_amdgcn_mfma_f32_16x16x32_bf16(ah, bh, acc[n], 0, 0, 0);
                acc[n] = __builtin_amdgcn_mfma_f32_16x16x32_bf16(ah, bl, acc[n], 0, 0, 0);
                acc[n] = __builtin_amdgcn_mfma_f32_16x16x32_bf16(al, bh, acc[n], 0, 0, 0);
            }
        }
        __syncthreads();
    }
    float* C = wppart + (long long)(slice * 3 + z) * 65536 + (long long)rowblk * 4096;
    #pragma unroll
    for (int n = 0; n < 4; ++n) {
        int col = n * 16 + rl;
        #pragma unroll
        for (int j = 0; j < 4; ++j) {
            int row = wave * 16 + kg * 4 + j;
            C[row * 64 + col] = acc[n][j];
        }
    }
}

// ---------------- K2: reduce Wp -> WpT bf16 planes; Weff; lam. grid 257.
__global__ __launch_bounds__(256) void wpfix(
    const float* __restrict__ wppart, const float* __restrict__ RW,
    const float* __restrict__ q1v, const float* __restrict__ k1v,
    const float* __restrict__ q2v, const float* __restrict__ k2v,
    const float* __restrict__ lam0,
    ushort_t* __restrict__ WpThi, ushort_t* __restrict__ WpTlo,
    float* __restrict__ Weff, float* __restrict__ lamOut)
{
    __shared__ float red[2][4];
    int bid = blockIdx.x, tid = threadIdx.x;
    if (bid < 192) {
        int f4i = bid * 256 + tid;          // [1024 rows][48 f4-cols]
        int row = f4i / 48, cq = f4i % 48;
        int c4 = cq * 4, z = c4 >> 6, cl = c4 & 63;
        float4 s = {0.f, 0.f, 0.f, 0.f};
        #pragma unroll
        for (int sl = 0; sl < 8; ++sl) {
            float4 m = *(const float4*)&wppart[(long long)(sl * 3 + z) * 65536 + (long long)row * 64 + cl];
            s.x += m.x; s.y += m.y; s.z += m.z; s.w += m.w;
        }
        float vv[4] = {s.x, s.y, s.z, s.w};
        #pragma unroll
        for (int j = 0; j < 4; ++j) {
            ushort_t h, l; split2(vv[j], h, l);
            WpThi[(long long)(c4 + j) * 1024 + row] = h;
            WpTlo[(long long)(c4 + j) * 1024 + row] = l;
        }
    } else if (bid < 256) {
        int f4i = (bid - 192) * 256 + tid;  // 16384 f4 over Weff[64][1024]
        int p = f4i >> 8, e4 = (f4i & 255) * 4;
        float4 s = {0.f, 0.f, 0.f, 0.f};
        #pragma unroll
        for (int h = 0; h < 16; ++h) {
            float4 r = *(const float4*)&RW[(long long)(h * 64 + p) * 1024 + e4];
            float m = (float)(h + 1);
            s.x += m * r.x; s.y += m * r.y; s.z += m * r.z; s.w += m * r.w;
        }
        *(float4*)&Weff[(long long)p * 1024 + e4] = s;
    } else {
        float d1 = 0.f, d2 = 0.f;
        for (int i = tid; i < 1024; i += 256) {
            d1 += q1v[i] * k1v[i];
            d2 += q2v[i] * k2v[i];
        }
        #pragma unroll
        for (int off = 32; off > 0; off >>= 1) {
            d1 += __shfl_down(d1, off);
            d2 += __shfl_down(d2, off);
        }
        int wave = tid >> 6;
        if ((tid & 63) == 0) { red[0][wave] = d1; red[1][wave] = d2; }
        __syncthreads();
        if (tid == 0) {
            float s1 = red[0][0] + red[0][1] + red[0][2] + red[0][3];
            float s2 = red[1][0] + red[1][1] + red[1][2] + red[1][3];
            *lamOut = expf(s1) - expf(s2) + lam0[0];
        }
    }
}

// ---------------- K3: qkv z-fused split-K partials. grid 512 = rowblk(64) + 64*slice(8)
__global__ __launch_bounds__(256) void qkv_fused(
    const float* __restrict__ x,
    const ushort_t* __restrict__ WpThi, const ushort_t* __restrict__ WpTlo,
    float* __restrict__ qpart)
{
    __shared__ __align__(16) ushort_t Ah[4096], Al[4096], Bh[3][4096], Bl[3][4096];
    int bid = blockIdx.x;
    int rowblk = bid & 63, slice = bid >> 6;
    long long row0 = (long long)rowblk * 64;

    int tid = threadIdx.x;
    int wave = tid >> 6, lane = tid & 63;
    int rl = lane & 15, kg = lane >> 4;
    f32x4 acc[3][4] = {};

    int k0 = slice * 128;
    for (int ch = 0; ch < 2; ++ch, k0 += 64) {
        // stage A: x rows, split once for all 3 z
        #pragma unroll
        for (int i = 0; i < 4; ++i) {
            int pos = tid + 256 * i;
            int r = pos >> 4, k4 = (pos & 15) * 4;
            float4 v = *(const float4*)&x[(row0 + r) * 1024 + k0 + k4];
            ushort4 h, l;
            split2(v.x, h.x, l.x); split2(v.y, h.y, l.y);
            split2(v.z, h.z, l.z); split2(v.w, h.w, l.w);
            int idx = swzA(r, k4);
            *(ushort4*)&Ah[idx] = h;
            *(ushort4*)&Al[idx] = l;
        }
        // stage B: 3 z planes (pure short8 copies, swizzled)
        #pragma unroll
        for (int z = 0; z < 3; ++z) {
            #pragma unroll
            for (int i = 0; i < 2; ++i) {
                int pos = tid + 256 * i;
                int n = pos >> 3, k8 = (pos & 7) * 8;
                int idx = swzA(n, k8);
                long long src = (long long)(z * 64 + n) * 1024 + k0 + k8;
                *(short8*)&Bh[z][idx] = *(const short8*)&WpThi[src];
                *(short8*)&Bl[z][idx] = *(const short8*)&WpTlo[src];
            }
        }
        __syncthreads();
        int ar = wave * 16 + rl;
        #pragma unroll
        for (int ks = 0; ks < 2; ++ks) {
            int kb = ks * 32 + kg * 8;
            short8 ah = *(const short8*)&Ah[swzA(ar, kb)];
            short8 al = *(const short8*)&Al[swzA(ar, kb)];
            #pragma unroll
            for (int z = 0; z < 3; ++z) {
                #pragma unroll
                for (int n = 0; n < 4; ++n) {
                    int bi = swzA(n * 16 + rl, kb);
                    short8 bh = *(const short8*)&Bh[z][bi];
                    short8 bl = *(const short8*)&Bl[z][bi];
                    acc[z][n] = __builtin_amdgcn_mfma_f32_16x16x32_bf16(ah, bh, acc[z][n], 0, 0, 0);
                    acc[z][n] = __builtin_amdgcn_mfma_f32_16x16x32_bf16(ah, bl, acc[z][n], 0, 0, 0);
                    acc[z][n] = __builtin_amdgcn_mfma_f32_16x16x32_bf16(al, bh, acc[z][n], 0, 0, 0);
                }
            }
        }
        __syncthreads();
    }
    #pragma unroll
    for (int z = 0; z < 3; ++z) {
        float* C = qpart + (long long)(slice * 3 + z) * 262144;
        #pragma unroll
        for (int n = 0; n < 4; ++n) {
            int col = n * 16 + rl;
            #pragma unroll
            for (int j = 0; j < 4; ++j) {
                long long row = row0 + wave * 16 + kg * 4 + j;
                C[row * 64 + col] = acc[z][n][j];
            }
        }
    }
}

// ---------------- K4: M partials (reduce k,v inline) + Q plane reduce. grid 96.
__global__ __launch_bounds__(256) void mpartq(
    const float* __restrict__ qpart, const float* __restrict__ proj_b,
    float* __restrict__ Mpart, ushort_t* __restrict__ Qhi, ushort_t* __restrict__ Qlo)
{
    int bid = blockIdx.x, tid = threadIdx.x;
    if (bid < 64) {
        int ks = bid & 31, b = bid >> 5;
        __shared__ float ksh[64][68];
        __shared__ float vsh[64][68];
        long long row0 = (long long)b * 2048 + ks * 64;
        #pragma unroll
        for (int i = 0; i < 8; ++i) {
            int pos = tid + 256 * i;        // [arr(2)][row(64)][c4(16)]
            int arr = pos >> 10, rem = pos & 1023;
            int r = rem >> 4, c4 = (rem & 15) * 4;
            float4 s = *(const float4*)&proj_b[c4];
            long long off = (row0 + r) * 64 + c4;
            #pragma unroll
            for (int sl = 0; sl < 8; ++sl) {
                float4 m = *(const float4*)&qpart[(long long)(sl * 3 + 1 + arr) * 262144 + off];
                s.x += m.x; s.y += m.y; s.z += m.z; s.w += m.w;
            }
            if (arr == 0) *(float4*)&ksh[r][c4] = s;
            else          *(float4*)&vsh[r][c4] = s;
        }
        __syncthreads();
        int p = tid & 63, cg = tid >> 6;
        float acc[16] = {};
        for (int s = 0; s < 64; ++s) {
            float vv = vsh[s][p];
            float4 k0 = *(const float4*)&ksh[s][cg * 16];
            float4 k1 = *(const float4*)&ksh[s][cg * 16 + 4];
            float4 k2 = *(const float4*)&ksh[s][cg * 16 + 8];
            float4 k3 = *(const float4*)&ksh[s][cg * 16 + 12];
            acc[0] += k0.x * vv;  acc[1] += k0.y * vv;  acc[2] += k0.z * vv;  acc[3] += k0.w * vv;
            acc[4] += k1.x * vv;  acc[5] += k1.y * vv;  acc[6] += k1.z * vv;  acc[7] += k1.w * vv;
            acc[8] += k2.x * vv;  acc[9] += k2.y * vv;  acc[10] += k2.z * vv; acc[11] += k2.w * vv;
            acc[12] += k3.x * vv; acc[13] += k3.y * vv; acc[14] += k3.z * vv; acc[15] += k3.w * vv;
        }
        float* o = Mpart + (long long)b * 131072 + (long long)ks * 4096;
        #pragma unroll
        for (int ci = 0; ci < 16; ++ci)
            o[(cg * 16 + ci) * 64 + p] = acc[ci];
    } else {
        int qb = bid - 64;                  // 32 blocks x 128 rows
        long long row0 = (long long)qb * 128;
        #pragma unroll
        for (int i = 0; i < 8; ++i) {
            int pos = tid + 256 * i;        // [row(128)][c4(16)]
            int r = pos >> 4, c4 = (pos & 15) * 4;
            float4 s = *(const float4*)&proj_b[c4];
            long long off = (row0 + r) * 64 + c4;
            #pragma unroll
            for (int sl = 0; sl < 8; ++sl) {
                float4 m = *(const float4*)&qpart[(long long)(sl * 3) * 262144 + off];
                s.x += m.x; s.y += m.y; s.z += m.z; s.w += m.w;
            }
            ushort4 h, l;
            split2(s.x, h.x, l.x); split2(s.y, h.y, l.y);
            split2(s.z, h.z, l.z); split2(s.w, h.w, l.w);
            *(ushort4*)&Qhi[off] = h;
            *(ushort4*)&Qlo[off] = l;
        }
    }
}

// ---------------- K5: Meff = coef*sum(Mpart); G = Meff @ Weff -> GT planes. grid 32.
__global__ __launch_bounds__(256) void gkern(
    const float* __restrict__ Mpart, const float* __restrict__ Weff,
    const float* __restrict__ lamp,
    ushort_t* __restrict__ GThi, ushort_t* __restrict__ GTlo)
{
    int colblk = blockIdx.x & 15, b = blockIdx.x >> 4;
    __shared__ float As[64][68];
    __shared__ float Bs[64][68];
    int tid = threadIdx.x;
    float lam = *lamp;
    #pragma unroll
    for (int i = 0; i < 4; ++i) {
        int pos = tid + 256 * i;        // 1024 f4 over Meff[64][64]
        int c = pos >> 4, p4 = (pos & 15) * 4;
        float4 s = {0.f, 0.f, 0.f, 0.f};
        #pragma unroll 8
        for (int ks = 0; ks < 32; ++ks) {
            float4 m = *(const float4*)&Mpart[(long long)b * 131072 + (long long)ks * 4096 + c * 64 + p4];
            s.x += m.x; s.y += m.y; s.z += m.z; s.w += m.w;
        }
        float coef = 0.125f * (c < 32 ? 1.0f : -lam);
        s.x *= coef; s.y *= coef; s.z *= coef; s.w *= coef;
        *(float4*)&As[c][p4] = s;
    }
    #pragma unroll
    for (int i = 0; i < 4; ++i) {
        int pos = tid + 256 * i;
        int kk = pos >> 4, n4 = (pos & 15) * 4;
        *(float4*)&Bs[kk][n4] = *(const float4*)&Weff[(long long)kk * 1024 + colblk * 64 + n4];
    }
    __syncthreads();

    int tx = tid & 15, ty = tid >> 4;
    float acc[4][4] = {};
    #pragma unroll 4
    for (int kk4 = 0; kk4 < 64; kk4 += 4) {
        float4 a4[4], b4[4];
        #pragma unroll
        for (int i = 0; i < 4; ++i) a4[i] = *(const float4*)&As[ty * 4 + i][kk4];
        #pragma unroll
        for (int r = 0; r < 4; ++r) b4[r] = *(const float4*)&Bs[kk4 + r][tx * 4];
        #pragma unroll
        for (int i = 0; i < 4; ++i) {
            acc[i][0] += a4[i].x * b4[0].x + a4[i].y * b4[1].x + a4[i].z * b4[2].x + a4[i].w * b4[3].x;
            acc[i][1] += a4[i].x * b4[0].y + a4[i].y * b4[1].y + a4[i].z * b4[2].y + a4[i].w * b4[3].y;
            acc[i][2] += a4[i].x * b4[0].z + a4[i].y * b4[1].z + a4[i].z * b4[2].z + a4[i].w * b4[3].z;
            acc[i][3] += a4[i].x * b4[0].w + a4[i].y * b4[1].w + a4[i].z * b4[2].w + a4[i].w * b4[3].w;
        }
    }
    #pragma unroll
    for (int i = 0; i < 4; ++i)
        #pragma unroll
        for (int j = 0; j < 4; ++j) {
            ushort_t h, l; split2(acc[i][j], h, l);
            long long idx = (long long)b * 65536 + (long long)(colblk * 64 + tx * 4 + j) * 64 + ty * 4 + i;
            GThi[idx] = h; GTlo[idx] = l;
        }
}

// ---------------- K6: out = Q @ G (pure plane loads + MFMA). grid 1024.
__global__ __launch_bounds__(256) void outk(
    const ushort_t* __restrict__ Qhi, const ushort_t* __restrict__ Qlo,
    const ushort_t* __restrict__ GThi, const ushort_t* __restrict__ GTlo,
    float* __restrict__ out)
{
    __shared__ __align__(16) ushort_t Ah[4096], Al[4096], Bh[4096], Bl[4096];
    int bid = blockIdx.x;
    int rowblk = bid & 31, colblk = (bid >> 5) & 15, b = bid >> 9;
    int tid = threadIdx.x;
    long long row0 = (long long)b * 2048 + rowblk * 64;

    #pragma unroll
    for (int i = 0; i < 2; ++i) {
        int pos = tid + 256 * i;
        int n = pos >> 3, k8 = (pos & 7) * 8;
        int idx = swzA(n, k8);
        long long qsrc = (row0 + n) * 64 + k8;
        long long gsrc = (long long)b * 65536 + (long long)(colblk * 64 + n) * 64 + k8;
        *(short8*)&Ah[idx] = *(const short8*)&Qhi[qsrc];
        *(short8*)&Al[idx] = *(const short8*)&Qlo[qsrc];
        *(short8*)&Bh[idx] = *(const short8*)&GThi[gsrc];
        *(short8*)&Bl[idx] = *(const short8*)&GTlo[gsrc];
    }
    __syncthreads();

    int wave = tid >> 6, lane = tid & 63;
    int rl = lane & 15, kg = lane >> 4;
    f32x4 acc[4] = {};
    int ar = wave * 16 + rl;
    #pragma unroll
    for (int ks = 0; ks < 2; ++ks) {
        int kb = ks * 32 + kg * 8;
        short8 ah = *(const short8*)&Ah[swzA(ar, kb)];
        short8 al = *(const short8*)&Al[swzA(ar, kb)];
        #pragma unroll
        for (int n = 0; n < 4; ++n) {
            int bi = swzA(n * 16 + rl, kb);
            short8 bh = *(const short8*)&Bh[bi];
            short8 bl = *(const short8*)&Bl[bi];
            acc[n] = __builtin_amdgcn_mfma_f32_16x16x32_bf16(ah, bh, acc[n], 0, 0, 0);
            acc[n] = __builtin_amdgcn_mfma_f32_16x16x32_bf16(ah, bl, acc[n], 0, 0, 0);
            acc[n] = __builtin_amdgcn_mfma_f32_16x16x32_bf16(al, bh, acc[n], 0, 0, 0);
        }
    }
    #pragma unroll
    for (int n = 0; n < 4; ++n) {
        int col = colblk * 64 + n * 16 + rl;
        #pragma unroll
        for (int j = 0; j < 4; ++j) {
            int row = rowblk * 64 + wave * 16 + kg * 4 + j;
            out[(long long)b * 2097152 + (long long)row * 1024 + col] = acc[n][j];
        }
    }
}

extern "C" void kernel_launch(void* const* d_in, const int* in_sizes, int n_in,
                              void* d_out, int out_size, void* d_ws, size_t ws_size,
                              hipStream_t stream)
{
    const float* x      = (const float*)d_in[0];
    const float* WQ     = (const float*)d_in[1];
    const float* WK     = (const float*)d_in[2];
    const float* WV     = (const float*)d_in[3];
    const float* RW     = (const float*)d_in[4];
    const float* proj_w = (const float*)d_in[5];
    const float* proj_b = (const float*)d_in[6];
    const float* q1v    = (const float*)d_in[7];
    const float* k1v    = (const float*)d_in[8];
    const float* q2v    = (const float*)d_in[9];
    const float* k2v    = (const float*)d_in[10];
    const float* lam0   = (const float*)d_in[11];
    float* out = (float*)d_out;

    float* ws      = (float*)d_ws;
    float* wppart  = ws;                    // 24*65536  = 1,572,864
    float* qpart   = ws + 1572864;          // 24*262144 = 6,291,456
    float* Mpart   = ws + 7864320;          // 262,144
    float* Weff    = ws + 8126464;          // 65,536
    float* lam     = ws + 8192000;          // 16
    ushort_t* ub   = (ushort_t*)(ws + 8192064);
    ushort_t* WpThi = ub;                   // 196,608
    ushort_t* WpTlo = ub + 196608;
    ushort_t* Qhi   = ub + 393216;          // 262,144
    ushort_t* Qlo   = ub + 655360;
    ushort_t* GThi  = ub + 917504;          // 131,072
    ushort_t* GTlo  = ub + 1048576;

    dim3 blk(256);
    prep_sk<<<dim3(384), blk, 0, stream>>>(WQ, WK, WV, proj_w, wppart);
    wpfix<<<dim3(257), blk, 0, stream>>>(wppart, RW, q1v, k1v, q2v, k2v, lam0,
                                         WpThi, WpTlo, Weff, lam);
    qkv_fused<<<dim3(512), blk, 0, stream>>>(x, WpThi, WpTlo, qpart);
    mpartq<<<dim3(96), blk, 0, stream>>>(qpart, proj_b, Mpart, Qhi, Qlo);
    gkern<<<dim3(32), blk, 0, stream>>>(Mpart, Weff, lam, GThi, GTlo);
    outk<<<dim3(1024), blk, 0, stream>>>(Qhi, Qlo, GThi, GTlo, out);
}